// Round 6
// baseline (473.135 us; speedup 1.0000x reference)
//
#include <hip/hip_runtime.h>
#include <math.h>

#define NN 100000
#define NE 640000
#define MPAD 100032   // NN rounded up to 64
#define NBLK 98       // ceil(NN / 1024)

typedef __bf16 bf16_t;
typedef bf16_t bf16x8 __attribute__((ext_vector_type(8)));
typedef float  f32x4  __attribute__((ext_vector_type(4)));

// ================= CSR build =================

__global__ __launch_bounds__(256) void k_hist(const int* __restrict__ dst,
                                              int* __restrict__ deg) {
    int e = blockIdx.x * 256 + threadIdx.x;
    if (e < NE) atomicAdd(&deg[dst[e]], 1);
}

// block-level sums of deg (1024 elems per block)
__global__ __launch_bounds__(1024) void k_bsum(const int* __restrict__ deg,
                                               int* __restrict__ bsum) {
    __shared__ int warr[16];
    int t = threadIdx.x;
    int i = blockIdx.x * 1024 + t;
    int v = (i < NN) ? deg[i] : 0;
    int lane = t & 63, wid = t >> 6;
    #pragma unroll
    for (int off = 32; off > 0; off >>= 1) v += __shfl_xor(v, off, 64);
    if (lane == 0) warr[wid] = v;
    __syncthreads();
    if (t < 16) {
        int s = warr[t];
        #pragma unroll
        for (int off = 8; off > 0; off >>= 1) s += __shfl_xor(s, off, 64);
        if (t == 0) bsum[blockIdx.x] = s;
    }
}

// one wave scans NBLK block sums -> exclusive offsets
__global__ __launch_bounds__(64) void k_bscan(const int* __restrict__ bsum,
        int* __restrict__ boff, int* __restrict__ rowptr) {
    int lane = threadIdx.x;
    int carry = 0;
    for (int base = 0; base < NBLK; base += 64) {
        int i = base + lane;
        int v = (i < NBLK) ? bsum[i] : 0;
        int s = v;
        #pragma unroll
        for (int off = 1; off < 64; off <<= 1) {
            int u = __shfl_up(s, off, 64);
            if (lane >= off) s += u;
        }
        if (i < NBLK) boff[i] = carry + s - v;
        carry += __shfl(s, 63, 64);
    }
    if (lane == 0) rowptr[NN] = NE;
}

// per-block scan + global offset -> rowptr / cursor
__global__ __launch_bounds__(1024) void k_scan2(const int* __restrict__ deg,
        const int* __restrict__ boff, int* __restrict__ rowptr,
        int* __restrict__ cursor) {
    __shared__ int wsum[16];
    __shared__ int woff[16];
    int t = threadIdx.x;
    int lane = t & 63, wid = t >> 6;
    int i = blockIdx.x * 1024 + t;
    int v = (i < NN) ? deg[i] : 0;
    int s = v;
    #pragma unroll
    for (int off = 1; off < 64; off <<= 1) {
        int u = __shfl_up(s, off, 64);
        if (lane >= off) s += u;
    }
    if (lane == 63) wsum[wid] = s;
    __syncthreads();
    if (wid == 0) {
        int ws = (lane < 16) ? wsum[lane] : 0;
        #pragma unroll
        for (int off = 1; off < 16; off <<= 1) {
            int u = __shfl_up(ws, off, 64);
            if (lane >= off) ws += u;
        }
        if (lane < 16) woff[lane] = ws;
    }
    __syncthreads();
    if (i < NN) {
        int excl = boff[blockIdx.x] + (s - v) + (wid ? woff[wid - 1] : 0);
        rowptr[i] = excl;
        cursor[i] = excl;
    }
}

__global__ __launch_bounds__(256) void k_fill(const int* __restrict__ src,
        const int* __restrict__ dst, int* __restrict__ cursor,
        int* __restrict__ csr) {
    int e = blockIdx.x * 256 + threadIdx.x;
    if (e >= NE) return;
    int p = atomicAdd(&cursor[dst[e]], 1);
    csr[p] = src[e];
}

// ================= weight split (f32 -> hi/lo bf16) =================

__global__ __launch_bounds__(256) void k_split_w1(const float* __restrict__ W1l,
        const float* __restrict__ W1r, bf16_t* __restrict__ Wh,
        bf16_t* __restrict__ Wl) {
    int j = blockIdx.x, t = threadIdx.x;
    float f = (t < 128) ? W1l[j * 128 + t] : W1r[j * 128 + (t - 128)];
    bf16_t h = (bf16_t)f;
    bf16_t l = (bf16_t)(f - (float)h);
    Wh[j * 256 + t] = h;
    Wl[j * 256 + t] = l;
}

__global__ __launch_bounds__(256) void k_split_w2(const float* __restrict__ W2l,
        const float* __restrict__ W2r, bf16_t* __restrict__ Wh,
        bf16_t* __restrict__ Wl) {
    int j = blockIdx.x, t = threadIdx.x;
    float f = (j < 128) ? W2l[j * 256 + t] : W2r[(j - 128) * 256 + t];
    bf16_t h = (bf16_t)f;
    bf16_t l = (bf16_t)(f - (float)h);
    Wh[j * 256 + t] = h;
    Wl[j * 256 + t] = l;
}

// ================= gather-mean (f32, 128 wide, strided) =================

__global__ __launch_bounds__(256) void k_gather128s(const float* __restrict__ feat,
        int fstride, const int* __restrict__ rowptr, const int* __restrict__ csr,
        float* __restrict__ agg, int astride) {
    int tid = blockIdx.x * 256 + threadIdx.x;
    int node = tid >> 5;
    if (node >= NN) return;
    int lane4 = (tid & 31) << 2;
    int beg = rowptr[node], end = rowptr[node + 1];
    float4 acc = make_float4(0.f, 0.f, 0.f, 0.f);
    int e = beg;
    for (; e + 1 < end; e += 2) {
        int s0 = csr[e], s1 = csr[e + 1];
        float4 v0 = *(const float4*)(feat + (size_t)s0 * fstride + lane4);
        float4 v1 = *(const float4*)(feat + (size_t)s1 * fstride + lane4);
        acc.x += v0.x + v1.x; acc.y += v0.y + v1.y;
        acc.z += v0.z + v1.z; acc.w += v0.w + v1.w;
    }
    if (e < end) {
        int s0 = csr[e];
        float4 v0 = *(const float4*)(feat + (size_t)s0 * fstride + lane4);
        acc.x += v0.x; acc.y += v0.y; acc.z += v0.z; acc.w += v0.w;
    }
    float iv = 1.0f / (float)max(end - beg, 1);
    acc.x *= iv; acc.y *= iv; acc.z *= iv; acc.w *= iv;
    *(float4*)(agg + (size_t)node * astride + lane4) = acc;
}

// 2-wide gather-mean (layer 3)
__global__ __launch_bounds__(256) void k_gather2(const float* __restrict__ feat,
        const int* __restrict__ rowptr, const int* __restrict__ csr,
        float* __restrict__ agg) {
    int n = blockIdx.x * 256 + threadIdx.x;
    if (n >= NN) return;
    int beg = rowptr[n], end = rowptr[n + 1];
    float a0 = 0.f, a1 = 0.f;
    for (int e = beg; e < end; e++) {
        int s = csr[e];
        a0 += feat[2 * s];
        a1 += feat[2 * s + 1];
    }
    float iv = 1.0f / (float)max(end - beg, 1);
    agg[2 * n] = a0 * iv;
    agg[2 * n + 1] = a1 * iv;
}

// ================= split-bf16 MFMA GEMM =================
// C = A @ W^T with A,W f32 emulated as hi+lo bf16: C ~= Ah*Wh + Al*Wh + Ah*Wl
// block 256 = 4 waves; BM=64, BN=256 (wave owns 64 cols), BK=32.
// frag layouts (HW-verified m89/m120): A/B lane = [idx=lane&15][k=quad*8+j];
// C/D: col=lane&15, row=quad*4+reg.
// PADK=2: LDS row stride = 34 bf16 = 17 dwords (odd, co-prime with 32 banks)
// -> max 2-way bank aliasing on b128 reads/writes, which is free (m136).
// PADK=8 (20-dword stride) measured 7.2M conflict-cycles/dispatch.

#define PADK 2

__device__ __forceinline__ void split8(const float* __restrict__ p,
                                       bf16x8& h, bf16x8& l) {
    float4 v0 = *(const float4*)p;
    float4 v1 = *(const float4*)(p + 4);
    float f[8] = {v0.x, v0.y, v0.z, v0.w, v1.x, v1.y, v1.z, v1.w};
    #pragma unroll
    for (int i = 0; i < 8; i++) {
        bf16_t hi = (bf16_t)f[i];
        h[i] = hi;
        l[i] = (bf16_t)(f[i] - (float)hi);
    }
}

// Layer-1 GEMM, A = [agg | x]; fused epilogue h1 = relu(l2norm(C + b1))
__global__ __launch_bounds__(256) void k_gemm_l1(const float* __restrict__ Aa,
        const float* __restrict__ Ax, const bf16_t* __restrict__ Wh,
        const bf16_t* __restrict__ Wl, const float* __restrict__ bias,
        float* __restrict__ H) {
    __shared__ bf16_t sAh[64][32 + PADK], sAl[64][32 + PADK];
    __shared__ bf16_t sWh[256][32 + PADK], sWl[256][32 + PADK];
    __shared__ float pr[64][4];
    int t = threadIdx.x;
    int wave = t >> 6, lane = t & 63, quad = lane >> 4, l16 = lane & 15;
    int r0 = blockIdx.x * 64;
    f32x4 acc[4][4] = {};
    int arow = t >> 2, aseg = t & 3;
    int grow = r0 + arow; if (grow >= NN) grow = NN - 1;
    for (int k0 = 0; k0 < 256; k0 += 32) {
        const float* Asrc = (k0 < 128) ? Aa : Ax;
        int kb = (k0 < 128) ? k0 : (k0 - 128);
        bf16x8 h8, l8;
        split8(&Asrc[(size_t)grow * 128 + kb + aseg * 8], h8, l8);
        *(bf16x8*)&sAh[arow][aseg * 8] = h8;
        *(bf16x8*)&sAl[arow][aseg * 8] = l8;
        #pragma unroll
        for (int i = 0; i < 4; i++) {
            int wr = arow + i * 64;
            *(bf16x8*)&sWh[wr][aseg * 8] = *(const bf16x8*)&Wh[(size_t)wr * 256 + k0 + aseg * 8];
            *(bf16x8*)&sWl[wr][aseg * 8] = *(const bf16x8*)&Wl[(size_t)wr * 256 + k0 + aseg * 8];
        }
        __syncthreads();
        bf16x8 ah[4], al[4], bh[4], bl[4];
        #pragma unroll
        for (int mt = 0; mt < 4; mt++) {
            ah[mt] = *(bf16x8*)&sAh[mt * 16 + l16][quad * 8];
            al[mt] = *(bf16x8*)&sAl[mt * 16 + l16][quad * 8];
        }
        #pragma unroll
        for (int nt = 0; nt < 4; nt++) {
            bh[nt] = *(bf16x8*)&sWh[wave * 64 + nt * 16 + l16][quad * 8];
            bl[nt] = *(bf16x8*)&sWl[wave * 64 + nt * 16 + l16][quad * 8];
        }
        #pragma unroll
        for (int mt = 0; mt < 4; mt++)
            #pragma unroll
            for (int nt = 0; nt < 4; nt++) {
                acc[mt][nt] = __builtin_amdgcn_mfma_f32_16x16x32_bf16(ah[mt], bh[nt], acc[mt][nt], 0, 0, 0);
                acc[mt][nt] = __builtin_amdgcn_mfma_f32_16x16x32_bf16(al[mt], bh[nt], acc[mt][nt], 0, 0, 0);
                acc[mt][nt] = __builtin_amdgcn_mfma_f32_16x16x32_bf16(ah[mt], bl[nt], acc[mt][nt], 0, 0, 0);
            }
        __syncthreads();
    }
    float bcol[4];
    #pragma unroll
    for (int nt = 0; nt < 4; nt++) bcol[nt] = bias[wave * 64 + nt * 16 + l16];
    #pragma unroll
    for (int mt = 0; mt < 4; mt++)
        #pragma unroll
        for (int nt = 0; nt < 4; nt++)
            #pragma unroll
            for (int rg = 0; rg < 4; rg++)
                acc[mt][nt][rg] += bcol[nt];
    float ss[4][4];
    #pragma unroll
    for (int mt = 0; mt < 4; mt++)
        #pragma unroll
        for (int rg = 0; rg < 4; rg++) {
            float s = 0.f;
            #pragma unroll
            for (int nt = 0; nt < 4; nt++) s += acc[mt][nt][rg] * acc[mt][nt][rg];
            #pragma unroll
            for (int off = 1; off < 16; off <<= 1) s += __shfl_xor(s, off, 64);
            ss[mt][rg] = s;
        }
    if (l16 == 0) {
        #pragma unroll
        for (int mt = 0; mt < 4; mt++)
            #pragma unroll
            for (int rg = 0; rg < 4; rg++)
                pr[mt * 16 + quad * 4 + rg][wave] = ss[mt][rg];
    }
    __syncthreads();
    #pragma unroll
    for (int mt = 0; mt < 4; mt++)
        #pragma unroll
        for (int rg = 0; rg < 4; rg++) {
            int lr = mt * 16 + quad * 4 + rg;
            int row = r0 + lr;
            if (row >= NN) continue;
            float tot = pr[lr][0] + pr[lr][1] + pr[lr][2] + pr[lr][3];
            float inv = 1.0f / fmaxf(sqrtf(tot), 1e-12f);
            #pragma unroll
            for (int nt = 0; nt < 4; nt++) {
                int col = wave * 64 + nt * 16 + l16;
                H[(size_t)row * 256 + col] = fmaxf(acc[mt][nt][rg] * inv, 0.f);
            }
        }
}

// Layer-2 GEMM: C2 = h1 @ [W2l;W2r]^T, plain f32 store
__global__ __launch_bounds__(256) void k_gemm_l2(const float* __restrict__ A,
        const bf16_t* __restrict__ Wh, const bf16_t* __restrict__ Wl,
        float* __restrict__ C) {
    __shared__ bf16_t sAh[64][32 + PADK], sAl[64][32 + PADK];
    __shared__ bf16_t sWh[256][32 + PADK], sWl[256][32 + PADK];
    int t = threadIdx.x;
    int wave = t >> 6, lane = t & 63, quad = lane >> 4, l16 = lane & 15;
    int r0 = blockIdx.x * 64;
    f32x4 acc[4][4] = {};
    int arow = t >> 2, aseg = t & 3;
    int grow = r0 + arow; if (grow >= NN) grow = NN - 1;
    for (int k0 = 0; k0 < 256; k0 += 32) {
        bf16x8 h8, l8;
        split8(&A[(size_t)grow * 256 + k0 + aseg * 8], h8, l8);
        *(bf16x8*)&sAh[arow][aseg * 8] = h8;
        *(bf16x8*)&sAl[arow][aseg * 8] = l8;
        #pragma unroll
        for (int i = 0; i < 4; i++) {
            int wr = arow + i * 64;
            *(bf16x8*)&sWh[wr][aseg * 8] = *(const bf16x8*)&Wh[(size_t)wr * 256 + k0 + aseg * 8];
            *(bf16x8*)&sWl[wr][aseg * 8] = *(const bf16x8*)&Wl[(size_t)wr * 256 + k0 + aseg * 8];
        }
        __syncthreads();
        bf16x8 ah[4], al[4], bh[4], bl[4];
        #pragma unroll
        for (int mt = 0; mt < 4; mt++) {
            ah[mt] = *(bf16x8*)&sAh[mt * 16 + l16][quad * 8];
            al[mt] = *(bf16x8*)&sAl[mt * 16 + l16][quad * 8];
        }
        #pragma unroll
        for (int nt = 0; nt < 4; nt++) {
            bh[nt] = *(bf16x8*)&sWh[wave * 64 + nt * 16 + l16][quad * 8];
            bl[nt] = *(bf16x8*)&sWl[wave * 64 + nt * 16 + l16][quad * 8];
        }
        #pragma unroll
        for (int mt = 0; mt < 4; mt++)
            #pragma unroll
            for (int nt = 0; nt < 4; nt++) {
                acc[mt][nt] = __builtin_amdgcn_mfma_f32_16x16x32_bf16(ah[mt], bh[nt], acc[mt][nt], 0, 0, 0);
                acc[mt][nt] = __builtin_amdgcn_mfma_f32_16x16x32_bf16(al[mt], bh[nt], acc[mt][nt], 0, 0, 0);
                acc[mt][nt] = __builtin_amdgcn_mfma_f32_16x16x32_bf16(ah[mt], bl[nt], acc[mt][nt], 0, 0, 0);
            }
        __syncthreads();
    }
    #pragma unroll
    for (int mt = 0; mt < 4; mt++)
        #pragma unroll
        for (int rg = 0; rg < 4; rg++) {
            int row = r0 + mt * 16 + quad * 4 + rg;
            if (row >= NN) continue;
            #pragma unroll
            for (int nt = 0; nt < 4; nt++) {
                int col = wave * 64 + nt * 16 + l16;
                C[(size_t)row * 256 + col] = acc[mt][nt][rg];
            }
        }
}

// ==== layer2 epilogue + fused q3: h2 = relu(norm(agg2+r2+b2)); q3 = h2 @ W3l^T ===
// half-wave (32 lanes) per row; lane covers 4 elems of the 128-wide row

__global__ __launch_bounds__(256) void k_combine128(const float* __restrict__ agg2,
        const float* __restrict__ C2, const float* __restrict__ b2,
        const float* __restrict__ W3l, float* __restrict__ h2,
        float* __restrict__ q3) {
    __shared__ float sw[256];
    int t = threadIdx.x;
    sw[t] = W3l[t];
    __syncthreads();
    int tid = blockIdx.x * 256 + t;
    int row = tid >> 5, l = tid & 31;
    if (row >= NN) return;
    float4 a = *(const float4*)&agg2[(size_t)row * 128 + l * 4];
    float4 r = *(const float4*)&C2[(size_t)row * 256 + 128 + l * 4];
    float4 b = *(const float4*)&b2[l * 4];
    float v0 = a.x + r.x + b.x;
    float v1 = a.y + r.y + b.y;
    float v2 = a.z + r.z + b.z;
    float v3 = a.w + r.w + b.w;
    float s = v0 * v0 + v1 * v1 + v2 * v2 + v3 * v3;
    #pragma unroll
    for (int off = 16; off > 0; off >>= 1) s += __shfl_xor(s, off, 64);
    float invn = 1.0f / fmaxf(sqrtf(s), 1e-12f);
    float4 o;
    o.x = fmaxf(v0 * invn, 0.f); o.y = fmaxf(v1 * invn, 0.f);
    o.z = fmaxf(v2 * invn, 0.f); o.w = fmaxf(v3 * invn, 0.f);
    *(float4*)&h2[(size_t)row * 128 + l * 4] = o;
    float a0 = o.x * sw[l*4] + o.y * sw[l*4+1] + o.z * sw[l*4+2] + o.w * sw[l*4+3];
    float a1 = o.x * sw[128+l*4] + o.y * sw[129+l*4] + o.z * sw[130+l*4] + o.w * sw[131+l*4];
    #pragma unroll
    for (int off = 16; off > 0; off >>= 1) {
        a0 += __shfl_xor(a0, off, 64);
        a1 += __shfl_xor(a1, off, 64);
    }
    if (l == 0) {
        q3[2 * row] = a0;
        q3[2 * row + 1] = a1;
    }
}

// ================= final =================

__global__ __launch_bounds__(256) void k_final(const float* __restrict__ h2,
        const float* __restrict__ W3r, const float* __restrict__ b3,
        const float* __restrict__ aggq, float* __restrict__ out) {
    __shared__ float sw[256];
    int t = threadIdx.x;
    sw[t] = W3r[t];
    __syncthreads();
    int i = blockIdx.x * 256 + t;
    if (i >= NN) return;
    const float4* row = (const float4*)(h2 + (size_t)i * 128);
    float a0 = 0.f, a1 = 0.f;
    #pragma unroll
    for (int q = 0; q < 32; q++) {
        float4 v = row[q];
        a0 += v.x * sw[4*q] + v.y * sw[4*q+1] + v.z * sw[4*q+2] + v.w * sw[4*q+3];
        a1 += v.x * sw[128+4*q] + v.y * sw[129+4*q] + v.z * sw[130+4*q] + v.w * sw[131+4*q];
    }
    float v0 = aggq[2 * i] + a0 + b3[0];
    float v1 = aggq[2 * i + 1] + a1 + b3[1];
    float invn = 1.0f / fmaxf(sqrtf(v0 * v0 + v1 * v1), 1e-12f);
    v0 *= invn; v1 *= invn;
    float mx = fmaxf(v0, v1);
    float l = logf(expf(v0 - mx) + expf(v1 - mx));
    out[2 * i] = v0 - mx - l;
    out[2 * i + 1] = v1 - mx - l;
}

// ================= launch =================

extern "C" void kernel_launch(void* const* d_in, const int* in_sizes, int n_in,
                              void* d_out, int out_size, void* d_ws, size_t ws_size,
                              hipStream_t stream) {
    const float* x   = (const float*)d_in[0];
    const int*   ei  = (const int*)d_in[1];
    const float* W1l = (const float*)d_in[2];
    const float* W1r = (const float*)d_in[3];
    const float* b1  = (const float*)d_in[4];
    const float* W2l = (const float*)d_in[5];
    const float* W2r = (const float*)d_in[6];
    const float* b2  = (const float*)d_in[7];
    const float* W3l = (const float*)d_in[8];
    const float* W3r = (const float*)d_in[9];
    const float* b3  = (const float*)d_in[10];
    float* out = (float*)d_out;
    const int* src = ei;
    const int* dst = ei + NE;

    // ---- workspace layout ----
    int* deg    = (int*)d_ws;                     // 102400
    int* rowptr = deg + 102400;
    int* cursor = rowptr + 102400;
    int* csr    = cursor + 102400;                // 655360
    int* bsum   = csr + 655360;                   // 128
    int* boff   = bsum + 128;                     // 128
    bf16_t* W1h  = (bf16_t*)(boff + 128);         // 65536 bf16 each
    bf16_t* W1lo = W1h + 65536;
    bf16_t* W2h  = W1lo + 65536;
    bf16_t* W2lo = W2h + 65536;
    float* aggA = (float*)(W2lo + 65536);         // 12.8M f32 (reused as agg2)
    float* h1   = aggA + 12800000;                // MPAD*256 f32 (reused as h2)
    float* C2   = h1 + (size_t)MPAD * 256;        // MPAD*256 f32
    float* q3   = C2 + (size_t)MPAD * 256;        // 200000
    float* aggq = q3 + 200000;                    // 200000
    float* h2   = h1;                             // reuse after L2 GEMM consumed h1

    // ---- CSR build (multi-block scan) ----
    hipMemsetAsync(deg, 0, NN * sizeof(int), stream);
    k_hist<<<(NE + 255) / 256, 256, 0, stream>>>(dst, deg);
    k_bsum<<<NBLK, 1024, 0, stream>>>(deg, bsum);
    k_bscan<<<1, 64, 0, stream>>>(bsum, boff, rowptr);
    k_scan2<<<NBLK, 1024, 0, stream>>>(deg, boff, rowptr, cursor);
    k_fill<<<(NE + 255) / 256, 256, 0, stream>>>(src, dst, cursor, csr);

    // ---- weight split ----
    k_split_w1<<<256, 256, 0, stream>>>(W1l, W1r, W1h, W1lo);
    k_split_w2<<<256, 256, 0, stream>>>(W2l, W2r, W2h, W2lo);

    // ---- layer 1 ----
    k_gather128s<<<(NN * 32 + 255) / 256, 256, 0, stream>>>(x, 128, rowptr, csr, aggA, 128);
    k_gemm_l1<<<MPAD / 64, 256, 0, stream>>>(aggA, x, W1h, W1lo, b1, h1);

    // ---- layer 2 ----
    k_gemm_l2<<<MPAD / 64, 256, 0, stream>>>(h1, W2h, W2lo, C2);
    k_gather128s<<<(NN * 32 + 255) / 256, 256, 0, stream>>>(C2, 256, rowptr, csr, aggA, 128);
    k_combine128<<<(NN * 32 + 255) / 256, 256, 0, stream>>>(aggA, C2, b2, W3l, h2, q3);

    // ---- layer 3 ----
    k_gather2<<<(NN + 255) / 256, 256, 0, stream>>>(q3, rowptr, csr, aggq);
    k_final<<<(NN + 255) / 256, 256, 0, stream>>>(h2, W3r, b3, aggq, out);
}

// Round 7
// 461.071 us; speedup vs baseline: 1.0262x; 1.0262x over previous
//
#include <hip/hip_runtime.h>
#include <math.h>

#define NN 100000
#define NE 640000
#define MPAD 100032   // NN rounded up to 64
#define NBLK 98       // ceil(NN / 1024)

typedef __bf16 bf16_t;
typedef bf16_t bf16x8 __attribute__((ext_vector_type(8)));
typedef float  f32x4  __attribute__((ext_vector_type(4)));

// ================= CSR build =================

__global__ __launch_bounds__(256) void k_hist(const int* __restrict__ dst,
                                              int* __restrict__ deg) {
    int e = blockIdx.x * 256 + threadIdx.x;
    if (e < NE) atomicAdd(&deg[dst[e]], 1);
}

__global__ __launch_bounds__(1024) void k_bsum(const int* __restrict__ deg,
                                               int* __restrict__ bsum) {
    __shared__ int warr[16];
    int t = threadIdx.x;
    int i = blockIdx.x * 1024 + t;
    int v = (i < NN) ? deg[i] : 0;
    int lane = t & 63, wid = t >> 6;
    #pragma unroll
    for (int off = 32; off > 0; off >>= 1) v += __shfl_xor(v, off, 64);
    if (lane == 0) warr[wid] = v;
    __syncthreads();
    if (t < 16) {
        int s = warr[t];
        #pragma unroll
        for (int off = 8; off > 0; off >>= 1) s += __shfl_xor(s, off, 64);
        if (t == 0) bsum[blockIdx.x] = s;
    }
}

__global__ __launch_bounds__(64) void k_bscan(const int* __restrict__ bsum,
        int* __restrict__ boff, int* __restrict__ rowptr) {
    int lane = threadIdx.x;
    int carry = 0;
    for (int base = 0; base < NBLK; base += 64) {
        int i = base + lane;
        int v = (i < NBLK) ? bsum[i] : 0;
        int s = v;
        #pragma unroll
        for (int off = 1; off < 64; off <<= 1) {
            int u = __shfl_up(s, off, 64);
            if (lane >= off) s += u;
        }
        if (i < NBLK) boff[i] = carry + s - v;
        carry += __shfl(s, 63, 64);
    }
    if (lane == 0) rowptr[NN] = NE;
}

__global__ __launch_bounds__(1024) void k_scan2(const int* __restrict__ deg,
        const int* __restrict__ boff, int* __restrict__ rowptr,
        int* __restrict__ cursor) {
    __shared__ int wsum[16];
    __shared__ int woff[16];
    int t = threadIdx.x;
    int lane = t & 63, wid = t >> 6;
    int i = blockIdx.x * 1024 + t;
    int v = (i < NN) ? deg[i] : 0;
    int s = v;
    #pragma unroll
    for (int off = 1; off < 64; off <<= 1) {
        int u = __shfl_up(s, off, 64);
        if (lane >= off) s += u;
    }
    if (lane == 63) wsum[wid] = s;
    __syncthreads();
    if (wid == 0) {
        int ws = (lane < 16) ? wsum[lane] : 0;
        #pragma unroll
        for (int off = 1; off < 16; off <<= 1) {
            int u = __shfl_up(ws, off, 64);
            if (lane >= off) ws += u;
        }
        if (lane < 16) woff[lane] = ws;
    }
    __syncthreads();
    if (i < NN) {
        int excl = boff[blockIdx.x] + (s - v) + (wid ? woff[wid - 1] : 0);
        rowptr[i] = excl;
        cursor[i] = excl;
    }
}

__global__ __launch_bounds__(256) void k_fill(const int* __restrict__ src,
        const int* __restrict__ dst, int* __restrict__ cursor,
        int* __restrict__ csr) {
    int e = blockIdx.x * 256 + threadIdx.x;
    if (e >= NE) return;
    int p = atomicAdd(&cursor[dst[e]], 1);
    csr[p] = src[e];
}

// ================= weight split (f32 -> hi/lo bf16) =================

__global__ __launch_bounds__(256) void k_split_w1(const float* __restrict__ W1l,
        const float* __restrict__ W1r, bf16_t* __restrict__ Wh,
        bf16_t* __restrict__ Wl) {
    int j = blockIdx.x, t = threadIdx.x;
    float f = (t < 128) ? W1l[j * 128 + t] : W1r[j * 128 + (t - 128)];
    bf16_t h = (bf16_t)f;
    bf16_t l = (bf16_t)(f - (float)h);
    Wh[j * 256 + t] = h;
    Wl[j * 256 + t] = l;
}

__global__ __launch_bounds__(256) void k_split_w2(const float* __restrict__ W2l,
        const float* __restrict__ W2r, bf16_t* __restrict__ Wh,
        bf16_t* __restrict__ Wl) {
    int j = blockIdx.x, t = threadIdx.x;
    float f = (j < 128) ? W2l[j * 256 + t] : W2r[(j - 128) * 256 + t];
    bf16_t h = (bf16_t)f;
    bf16_t l = (bf16_t)(f - (float)h);
    Wh[j * 256 + t] = h;
    Wl[j * 256 + t] = l;
}

// ================= gather-mean for layer 1 (f32, 128 wide) =================

__global__ __launch_bounds__(256) void k_gather128s(const float* __restrict__ feat,
        const int* __restrict__ rowptr, const int* __restrict__ csr,
        float* __restrict__ agg) {
    int tid = blockIdx.x * 256 + threadIdx.x;
    int node = tid >> 5;
    if (node >= NN) return;
    int lane4 = (tid & 31) << 2;
    int beg = rowptr[node], end = rowptr[node + 1];
    float4 acc = make_float4(0.f, 0.f, 0.f, 0.f);
    int e = beg;
    for (; e + 1 < end; e += 2) {
        int s0 = csr[e], s1 = csr[e + 1];
        float4 v0 = *(const float4*)(feat + (size_t)s0 * 128 + lane4);
        float4 v1 = *(const float4*)(feat + (size_t)s1 * 128 + lane4);
        acc.x += v0.x + v1.x; acc.y += v0.y + v1.y;
        acc.z += v0.z + v1.z; acc.w += v0.w + v1.w;
    }
    if (e < end) {
        int s0 = csr[e];
        float4 v0 = *(const float4*)(feat + (size_t)s0 * 128 + lane4);
        acc.x += v0.x; acc.y += v0.y; acc.z += v0.z; acc.w += v0.w;
    }
    float iv = 1.0f / (float)max(end - beg, 1);
    acc.x *= iv; acc.y *= iv; acc.z *= iv; acc.w *= iv;
    *(float4*)(agg + (size_t)node * 128 + lane4) = acc;
}

// ================= split-bf16 MFMA GEMM (register-prefetch pipelined) ==========
// C = A @ W^T with A,W f32 emulated as hi+lo bf16: C ~= Ah*Wh + Al*Wh + Ah*Wl
// block 256 = 4 waves; BM=64, BN=256 (wave owns 64 cols), BK=32, 8 k-iters.
// Pipeline: global loads for iter k+1 are issued right after the second barrier
// of iter k, so L2/HBM latency overlaps the MFMA section (the measured stall
// was the vmcnt(0) drain before the staging barrier at ~17% occupancy).
// PADK=2 -> LDS row stride 17 dwords (odd): conflict-free frag reads.

#define PADK 2

__device__ __forceinline__ void splitv(float4 v0, float4 v1,
                                       bf16x8& h, bf16x8& l) {
    float f[8] = {v0.x, v0.y, v0.z, v0.w, v1.x, v1.y, v1.z, v1.w};
    #pragma unroll
    for (int i = 0; i < 8; i++) {
        bf16_t hi = (bf16_t)f[i];
        h[i] = hi;
        l[i] = (bf16_t)(f[i] - (float)hi);
    }
}

// Layer-1 GEMM, A = [agg | x]; fused epilogue h1 = relu(l2norm(C + b1))
__global__ __launch_bounds__(256) void k_gemm_l1(const float* __restrict__ Aa,
        const float* __restrict__ Ax, const bf16_t* __restrict__ Wh,
        const bf16_t* __restrict__ Wl, const float* __restrict__ bias,
        float* __restrict__ H) {
    __shared__ bf16_t sAh[64][32 + PADK], sAl[64][32 + PADK];
    __shared__ bf16_t sWh[256][32 + PADK], sWl[256][32 + PADK];
    __shared__ float pr[64][4];
    int t = threadIdx.x;
    int wave = t >> 6, lane = t & 63, quad = lane >> 4, l16 = lane & 15;
    int r0 = blockIdx.x * 64;
    f32x4 acc[4][4] = {};
    int arow = t >> 2, aseg = t & 3;
    int grow = r0 + arow; if (grow >= NN) grow = NN - 1;
    // prefetch iter 0
    float4 pa0, pa1;
    bf16x8 pwh[4], pwl[4];
    {
        const float* p = &Aa[(size_t)grow * 128 + aseg * 8];
        pa0 = *(const float4*)p; pa1 = *(const float4*)(p + 4);
        #pragma unroll
        for (int i = 0; i < 4; i++) {
            int wr = arow + i * 64;
            pwh[i] = *(const bf16x8*)&Wh[(size_t)wr * 256 + aseg * 8];
            pwl[i] = *(const bf16x8*)&Wl[(size_t)wr * 256 + aseg * 8];
        }
    }
    for (int it = 0; it < 8; it++) {
        __syncthreads();   // prev iter's frag readers done
        bf16x8 h8, l8;
        splitv(pa0, pa1, h8, l8);
        *(bf16x8*)&sAh[arow][aseg * 8] = h8;
        *(bf16x8*)&sAl[arow][aseg * 8] = l8;
        #pragma unroll
        for (int i = 0; i < 4; i++) {
            int wr = arow + i * 64;
            *(bf16x8*)&sWh[wr][aseg * 8] = pwh[i];
            *(bf16x8*)&sWl[wr][aseg * 8] = pwl[i];
        }
        __syncthreads();
        if (it < 7) {       // issue next iter's loads; latency hides under MFMAs
            int k0n = (it + 1) * 32;
            const float* Asrc = (k0n < 128) ? Aa : Ax;
            int kb = (k0n < 128) ? k0n : (k0n - 128);
            const float* p = &Asrc[(size_t)grow * 128 + kb + aseg * 8];
            pa0 = *(const float4*)p; pa1 = *(const float4*)(p + 4);
            #pragma unroll
            for (int i = 0; i < 4; i++) {
                int wr = arow + i * 64;
                pwh[i] = *(const bf16x8*)&Wh[(size_t)wr * 256 + k0n + aseg * 8];
                pwl[i] = *(const bf16x8*)&Wl[(size_t)wr * 256 + k0n + aseg * 8];
            }
        }
        bf16x8 ah[4], al[4], bh[4], bl[4];
        #pragma unroll
        for (int mt = 0; mt < 4; mt++) {
            ah[mt] = *(bf16x8*)&sAh[mt * 16 + l16][quad * 8];
            al[mt] = *(bf16x8*)&sAl[mt * 16 + l16][quad * 8];
        }
        #pragma unroll
        for (int nt = 0; nt < 4; nt++) {
            bh[nt] = *(bf16x8*)&sWh[wave * 64 + nt * 16 + l16][quad * 8];
            bl[nt] = *(bf16x8*)&sWl[wave * 64 + nt * 16 + l16][quad * 8];
        }
        #pragma unroll
        for (int mt = 0; mt < 4; mt++)
            #pragma unroll
            for (int nt = 0; nt < 4; nt++) {
                acc[mt][nt] = __builtin_amdgcn_mfma_f32_16x16x32_bf16(ah[mt], bh[nt], acc[mt][nt], 0, 0, 0);
                acc[mt][nt] = __builtin_amdgcn_mfma_f32_16x16x32_bf16(al[mt], bh[nt], acc[mt][nt], 0, 0, 0);
                acc[mt][nt] = __builtin_amdgcn_mfma_f32_16x16x32_bf16(ah[mt], bl[nt], acc[mt][nt], 0, 0, 0);
            }
    }
    // ---- fused epilogue: bias, row L2-norm across 256 cols, relu ----
    float bcol[4];
    #pragma unroll
    for (int nt = 0; nt < 4; nt++) bcol[nt] = bias[wave * 64 + nt * 16 + l16];
    #pragma unroll
    for (int mt = 0; mt < 4; mt++)
        #pragma unroll
        for (int nt = 0; nt < 4; nt++)
            #pragma unroll
            for (int rg = 0; rg < 4; rg++)
                acc[mt][nt][rg] += bcol[nt];
    float ss[4][4];
    #pragma unroll
    for (int mt = 0; mt < 4; mt++)
        #pragma unroll
        for (int rg = 0; rg < 4; rg++) {
            float s = 0.f;
            #pragma unroll
            for (int nt = 0; nt < 4; nt++) s += acc[mt][nt][rg] * acc[mt][nt][rg];
            #pragma unroll
            for (int off = 1; off < 16; off <<= 1) s += __shfl_xor(s, off, 64);
            ss[mt][rg] = s;
        }
    __syncthreads();   // sA/sW dead; reuse barrier before pr
    if (l16 == 0) {
        #pragma unroll
        for (int mt = 0; mt < 4; mt++)
            #pragma unroll
            for (int rg = 0; rg < 4; rg++)
                pr[mt * 16 + quad * 4 + rg][wave] = ss[mt][rg];
    }
    __syncthreads();
    #pragma unroll
    for (int mt = 0; mt < 4; mt++)
        #pragma unroll
        for (int rg = 0; rg < 4; rg++) {
            int lr = mt * 16 + quad * 4 + rg;
            int row = r0 + lr;
            if (row >= NN) continue;
            float tot = pr[lr][0] + pr[lr][1] + pr[lr][2] + pr[lr][3];
            float inv = 1.0f / fmaxf(sqrtf(tot), 1e-12f);
            #pragma unroll
            for (int nt = 0; nt < 4; nt++) {
                int col = wave * 64 + nt * 16 + l16;
                H[(size_t)row * 256 + col] = fmaxf(acc[mt][nt][rg] * inv, 0.f);
            }
        }
}

// Layer-2 GEMM: C2 = h1 @ [W2l;W2r]^T, plain f32 store
__global__ __launch_bounds__(256) void k_gemm_l2(const float* __restrict__ A,
        const bf16_t* __restrict__ Wh, const bf16_t* __restrict__ Wl,
        float* __restrict__ C) {
    __shared__ bf16_t sAh[64][32 + PADK], sAl[64][32 + PADK];
    __shared__ bf16_t sWh[256][32 + PADK], sWl[256][32 + PADK];
    int t = threadIdx.x;
    int wave = t >> 6, lane = t & 63, quad = lane >> 4, l16 = lane & 15;
    int r0 = blockIdx.x * 64;
    f32x4 acc[4][4] = {};
    int arow = t >> 2, aseg = t & 3;
    int grow = r0 + arow; if (grow >= NN) grow = NN - 1;
    float4 pa0, pa1;
    bf16x8 pwh[4], pwl[4];
    {
        const float* p = &A[(size_t)grow * 256 + aseg * 8];
        pa0 = *(const float4*)p; pa1 = *(const float4*)(p + 4);
        #pragma unroll
        for (int i = 0; i < 4; i++) {
            int wr = arow + i * 64;
            pwh[i] = *(const bf16x8*)&Wh[(size_t)wr * 256 + aseg * 8];
            pwl[i] = *(const bf16x8*)&Wl[(size_t)wr * 256 + aseg * 8];
        }
    }
    for (int it = 0; it < 8; it++) {
        __syncthreads();
        bf16x8 h8, l8;
        splitv(pa0, pa1, h8, l8);
        *(bf16x8*)&sAh[arow][aseg * 8] = h8;
        *(bf16x8*)&sAl[arow][aseg * 8] = l8;
        #pragma unroll
        for (int i = 0; i < 4; i++) {
            int wr = arow + i * 64;
            *(bf16x8*)&sWh[wr][aseg * 8] = pwh[i];
            *(bf16x8*)&sWl[wr][aseg * 8] = pwl[i];
        }
        __syncthreads();
        if (it < 7) {
            int k0n = (it + 1) * 32;
            const float* p = &A[(size_t)grow * 256 + k0n + aseg * 8];
            pa0 = *(const float4*)p; pa1 = *(const float4*)(p + 4);
            #pragma unroll
            for (int i = 0; i < 4; i++) {
                int wr = arow + i * 64;
                pwh[i] = *(const bf16x8*)&Wh[(size_t)wr * 256 + k0n + aseg * 8];
                pwl[i] = *(const bf16x8*)&Wl[(size_t)wr * 256 + k0n + aseg * 8];
            }
        }
        bf16x8 ah[4], al[4], bh[4], bl[4];
        #pragma unroll
        for (int mt = 0; mt < 4; mt++) {
            ah[mt] = *(bf16x8*)&sAh[mt * 16 + l16][quad * 8];
            al[mt] = *(bf16x8*)&sAl[mt * 16 + l16][quad * 8];
        }
        #pragma unroll
        for (int nt = 0; nt < 4; nt++) {
            bh[nt] = *(bf16x8*)&sWh[wave * 64 + nt * 16 + l16][quad * 8];
            bl[nt] = *(bf16x8*)&sWl[wave * 64 + nt * 16 + l16][quad * 8];
        }
        #pragma unroll
        for (int mt = 0; mt < 4; mt++)
            #pragma unroll
            for (int nt = 0; nt < 4; nt++) {
                acc[mt][nt] = __builtin_amdgcn_mfma_f32_16x16x32_bf16(ah[mt], bh[nt], acc[mt][nt], 0, 0, 0);
                acc[mt][nt] = __builtin_amdgcn_mfma_f32_16x16x32_bf16(al[mt], bh[nt], acc[mt][nt], 0, 0, 0);
                acc[mt][nt] = __builtin_amdgcn_mfma_f32_16x16x32_bf16(ah[mt], bl[nt], acc[mt][nt], 0, 0, 0);
            }
    }
    #pragma unroll
    for (int mt = 0; mt < 4; mt++)
        #pragma unroll
        for (int rg = 0; rg < 4; rg++) {
            int row = r0 + mt * 16 + quad * 4 + rg;
            if (row >= NN) continue;
            #pragma unroll
            for (int nt = 0; nt < 4; nt++) {
                int col = wave * 64 + nt * 16 + l16;
                C[(size_t)row * 256 + col] = acc[mt][nt][rg];
            }
        }
}

// ==== fused layer-2 tail: gather-mean p2 + combine + norm + q3 ====
// 32 lanes per node; lane covers 4 f32 of the 128-wide row.
// Kills the agg2 intermediate (saves ~102 MB of HBM/L3 traffic).

__global__ __launch_bounds__(256) void k_gather_combine(const float* __restrict__ C2,
        const int* __restrict__ rowptr, const int* __restrict__ csr,
        const float* __restrict__ b2, const float* __restrict__ W3l,
        float* __restrict__ h2, float* __restrict__ q3) {
    __shared__ float sw[256];
    int t = threadIdx.x;
    sw[t] = W3l[t];
    __syncthreads();
    int tid = blockIdx.x * 256 + t;
    int node = tid >> 5;
    if (node >= NN) return;
    int l = tid & 31;
    int lane4 = l << 2;
    int beg = rowptr[node], end = rowptr[node + 1];
    float4 acc = make_float4(0.f, 0.f, 0.f, 0.f);
    int e = beg;
    for (; e + 1 < end; e += 2) {
        int s0 = csr[e], s1 = csr[e + 1];
        float4 v0 = *(const float4*)(C2 + (size_t)s0 * 256 + lane4);
        float4 v1 = *(const float4*)(C2 + (size_t)s1 * 256 + lane4);
        acc.x += v0.x + v1.x; acc.y += v0.y + v1.y;
        acc.z += v0.z + v1.z; acc.w += v0.w + v1.w;
    }
    if (e < end) {
        int s0 = csr[e];
        float4 v0 = *(const float4*)(C2 + (size_t)s0 * 256 + lane4);
        acc.x += v0.x; acc.y += v0.y; acc.z += v0.z; acc.w += v0.w;
    }
    float iv = 1.0f / (float)max(end - beg, 1);
    float4 r = *(const float4*)&C2[(size_t)node * 256 + 128 + lane4];
    float4 b = *(const float4*)&b2[lane4];
    float v0 = acc.x * iv + r.x + b.x;
    float v1 = acc.y * iv + r.y + b.y;
    float v2 = acc.z * iv + r.z + b.z;
    float v3 = acc.w * iv + r.w + b.w;
    float s = v0 * v0 + v1 * v1 + v2 * v2 + v3 * v3;
    #pragma unroll
    for (int off = 16; off > 0; off >>= 1) s += __shfl_xor(s, off, 64);
    float invn = 1.0f / fmaxf(sqrtf(s), 1e-12f);
    float4 o;
    o.x = fmaxf(v0 * invn, 0.f); o.y = fmaxf(v1 * invn, 0.f);
    o.z = fmaxf(v2 * invn, 0.f); o.w = fmaxf(v3 * invn, 0.f);
    *(float4*)&h2[(size_t)node * 128 + lane4] = o;
    float a0 = o.x * sw[lane4] + o.y * sw[lane4+1] + o.z * sw[lane4+2] + o.w * sw[lane4+3];
    float a1 = o.x * sw[128+lane4] + o.y * sw[129+lane4] + o.z * sw[130+lane4] + o.w * sw[131+lane4];
    #pragma unroll
    for (int off = 16; off > 0; off >>= 1) {
        a0 += __shfl_xor(a0, off, 64);
        a1 += __shfl_xor(a1, off, 64);
    }
    if (l == 0) {
        q3[2 * node] = a0;
        q3[2 * node + 1] = a1;
    }
}

// ================= final (absorbs the 2-wide q3 gather) =================

__global__ __launch_bounds__(256) void k_final(const float* __restrict__ h2,
        const float* __restrict__ W3r, const float* __restrict__ b3,
        const float* __restrict__ q3, const int* __restrict__ rowptr,
        const int* __restrict__ csr, float* __restrict__ out) {
    __shared__ float sw[256];
    int t = threadIdx.x;
    sw[t] = W3r[t];
    __syncthreads();
    int i = blockIdx.x * 256 + t;
    if (i >= NN) return;
    // gather-mean of q3 over neighbors
    int beg = rowptr[i], end = rowptr[i + 1];
    float g0 = 0.f, g1 = 0.f;
    for (int e = beg; e < end; e++) {
        int s = csr[e];
        g0 += q3[2 * s];
        g1 += q3[2 * s + 1];
    }
    float ivd = 1.0f / (float)max(end - beg, 1);
    g0 *= ivd; g1 *= ivd;
    const float4* row = (const float4*)(h2 + (size_t)i * 128);
    float a0 = 0.f, a1 = 0.f;
    #pragma unroll
    for (int q = 0; q < 32; q++) {
        float4 v = row[q];
        a0 += v.x * sw[4*q] + v.y * sw[4*q+1] + v.z * sw[4*q+2] + v.w * sw[4*q+3];
        a1 += v.x * sw[128+4*q] + v.y * sw[129+4*q] + v.z * sw[130+4*q] + v.w * sw[131+4*q];
    }
    float v0 = g0 + a0 + b3[0];
    float v1 = g1 + a1 + b3[1];
    float invn = 1.0f / fmaxf(sqrtf(v0 * v0 + v1 * v1), 1e-12f);
    v0 *= invn; v1 *= invn;
    float mx = fmaxf(v0, v1);
    float l = logf(expf(v0 - mx) + expf(v1 - mx));
    out[2 * i] = v0 - mx - l;
    out[2 * i + 1] = v1 - mx - l;
}

// ================= launch =================

extern "C" void kernel_launch(void* const* d_in, const int* in_sizes, int n_in,
                              void* d_out, int out_size, void* d_ws, size_t ws_size,
                              hipStream_t stream) {
    const float* x   = (const float*)d_in[0];
    const int*   ei  = (const int*)d_in[1];
    const float* W1l = (const float*)d_in[2];
    const float* W1r = (const float*)d_in[3];
    const float* b1  = (const float*)d_in[4];
    const float* W2l = (const float*)d_in[5];
    const float* W2r = (const float*)d_in[6];
    const float* b2  = (const float*)d_in[7];
    const float* W3l = (const float*)d_in[8];
    const float* W3r = (const float*)d_in[9];
    const float* b3  = (const float*)d_in[10];
    float* out = (float*)d_out;
    const int* src = ei;
    const int* dst = ei + NE;

    // ---- workspace layout ----
    int* deg    = (int*)d_ws;                     // 102400
    int* rowptr = deg + 102400;
    int* cursor = rowptr + 102400;
    int* csr    = cursor + 102400;                // 655360
    int* bsum   = csr + 655360;                   // 128
    int* boff   = bsum + 128;                     // 128
    bf16_t* W1h  = (bf16_t*)(boff + 128);         // 65536 bf16 each
    bf16_t* W1lo = W1h + 65536;
    bf16_t* W2h  = W1lo + 65536;
    bf16_t* W2lo = W2h + 65536;
    float* aggA = (float*)(W2lo + 65536);         // 12.8M f32 (layer-1 agg)
    float* h1   = aggA + 12800000;                // MPAD*256 f32 (reused as h2)
    float* C2   = h1 + (size_t)MPAD * 256;        // MPAD*256 f32
    float* q3   = C2 + (size_t)MPAD * 256;        // 200000
    float* h2   = h1;                             // reuse after L2 GEMM consumed h1

    // ---- CSR build (multi-block scan) ----
    hipMemsetAsync(deg, 0, NN * sizeof(int), stream);
    k_hist<<<(NE + 255) / 256, 256, 0, stream>>>(dst, deg);
    k_bsum<<<NBLK, 1024, 0, stream>>>(deg, bsum);
    k_bscan<<<1, 64, 0, stream>>>(bsum, boff, rowptr);
    k_scan2<<<NBLK, 1024, 0, stream>>>(deg, boff, rowptr, cursor);
    k_fill<<<(NE + 255) / 256, 256, 0, stream>>>(src, dst, cursor, csr);

    // ---- weight split ----
    k_split_w1<<<256, 256, 0, stream>>>(W1l, W1r, W1h, W1lo);
    k_split_w2<<<256, 256, 0, stream>>>(W2l, W2r, W2h, W2lo);

    // ---- layer 1 ----
    k_gather128s<<<(NN * 32 + 255) / 256, 256, 0, stream>>>(x, rowptr, csr, aggA);
    k_gemm_l1<<<MPAD / 64, 256, 0, stream>>>(aggA, x, W1h, W1lo, b1, h1);

    // ---- layer 2 (gather+combine+q3 fused) ----
    k_gemm_l2<<<MPAD / 64, 256, 0, stream>>>(h1, W2h, W2lo, C2);
    k_gather_combine<<<(NN * 32 + 255) / 256, 256, 0, stream>>>(C2, rowptr, csr, b2, W3l, h2, q3);

    // ---- layer 3 ----
    k_final<<<(NN + 255) / 256, 256, 0, stream>>>(h2, W3r, b3, q3, rowptr, csr, out);
}